// Round 1
// baseline (177.140 us; speedup 1.0000x reference)
//
#include <hip/hip_runtime.h>
#include <hip/hip_bf16.h>

// PFNN: out[n][b] = L3(tanh(L2(tanh(L1(tanh(L0(x)))))))  for B=4 branches,
// H=32, D_IN=3, N=1048576.  Strategy:
//  - f16 MFMA (16x16x32) computing out^T = W^T h^T per 16-point subtile.
//  - A-fragments (W^T) live in LDS (row-major [u][k], rows padded to 80B).
//  - Bias folded into MFMA C operand (layers 1,2) / into W0' row k=3 with
//    x-fragment k=3 = 1.0 (layer 0).
//  - Layer transition: tanh (exp2+rcp) -> v_cvt_pkrtz pack -> 8x ds_bpermute
//    redistribution from D-layout (col=lane&15=point, row=4g+i=unit; m89/m91)
//    into the next B-fragment (lane holds k=8g..8g+7 for point lane&15).
//  - Layer 3 (32->1): VALU dot + butterfly reduce over lanes {p,p+16,p+32,p+48}.
// Expected regime: transcendental/VALU-bound (~403M tanh), MFMA ~7us overlapped.

#define NPTS 1048576
constexpr int GRID_BLOCKS = 1024;

typedef _Float16 h8v __attribute__((ext_vector_type(8)));
typedef float f4v __attribute__((ext_vector_type(4)));

union H8 { h8v h; int i[4]; };

#if __has_builtin(__builtin_amdgcn_exp2f)
#define DEV_EXP2(x) __builtin_amdgcn_exp2f(x)
#else
#define DEV_EXP2(x) __builtin_exp2f(x)
#endif
#if __has_builtin(__builtin_amdgcn_rcpf)
#define DEV_RCP(x) __builtin_amdgcn_rcpf(x)
#else
#define DEV_RCP(x) (1.0f / (x))
#endif

__device__ __forceinline__ int pkrtz(float a, float b) {
  return __builtin_bit_cast(int, __builtin_amdgcn_cvt_pkrtz(a, b));
}

__device__ __forceinline__ float ftanh(float x) {
  // tanh(x) = 1 - 2/(1+e^{2x});  e^{2x} = exp2(x * 2*log2(e))
  float e = DEV_EXP2(x * 2.885390081777927f);
  float r = DEV_RCP(e + 1.0f);
  return fmaf(-2.0f, r, 1.0f);   // large x: e=inf -> r=0 -> 1; x<<0: e=0 -> -1
}

// tanh both accumulator tiles, pack to f16 pairs, redistribute into B-fragment.
__device__ __forceinline__ H8 make_bfrag(f4v a0, f4v a1, int addrA, int addrB,
                                         bool tsel) {
  float t00 = ftanh(a0[0]), t01 = ftanh(a0[1]), t02 = ftanh(a0[2]), t03 = ftanh(a0[3]);
  float t10 = ftanh(a1[0]), t11 = ftanh(a1[1]), t12 = ftanh(a1[2]), t13 = ftanh(a1[3]);
  int pk00 = pkrtz(t00, t01), pk01 = pkrtz(t02, t03);   // tile0 units (4g,4g+1),(4g+2,4g+3)
  int pk10 = pkrtz(t10, t11), pk11 = pkrtz(t12, t13);   // tile1 units 16+...
  int r0a = __builtin_amdgcn_ds_bpermute(addrA, pk00);
  int r0b = __builtin_amdgcn_ds_bpermute(addrA, pk10);
  int r1a = __builtin_amdgcn_ds_bpermute(addrA, pk01);
  int r1b = __builtin_amdgcn_ds_bpermute(addrA, pk11);
  int r2a = __builtin_amdgcn_ds_bpermute(addrB, pk00);
  int r2b = __builtin_amdgcn_ds_bpermute(addrB, pk10);
  int r3a = __builtin_amdgcn_ds_bpermute(addrB, pk01);
  int r3b = __builtin_amdgcn_ds_bpermute(addrB, pk11);
  H8 hf;
  hf.i[0] = tsel ? r0b : r0a;
  hf.i[1] = tsel ? r1b : r1a;
  hf.i[2] = tsel ? r2b : r2a;
  hf.i[3] = tsel ? r3b : r3a;
  return hf;
}

extern "C" __global__ void pfnn_kernel(
    const float* __restrict__ X,
    const float* __restrict__ W0, const float* __restrict__ B0,
    const float* __restrict__ W1, const float* __restrict__ B1,
    const float* __restrict__ W2, const float* __restrict__ B2,
    const float* __restrict__ W3, const float* __restrict__ B3,
    float* __restrict__ Out) {
  // LDS: W^T tables (A-fragment source), f32 biases / last-layer weights.
  __shared__ alignas(16) _Float16 lWT0[4][32][4];    // [b][u][k] k<3: W0, k==3: b0
  __shared__ alignas(16) _Float16 lWT1[4][32][40];   // [b][u][k], rows padded to 80B
  __shared__ alignas(16) _Float16 lWT2[4][32][40];
  __shared__ alignas(16) float lB1[4][32];
  __shared__ alignas(16) float lB2[4][32];
  __shared__ alignas(16) float lW3[4][32];
  __shared__ float lb3[4];

  const int tid = threadIdx.x;
  for (int idx = tid; idx < 512; idx += 256) {
    int b = idx >> 7, u = (idx >> 2) & 31, k = idx & 3;
    float v = (k < 3) ? W0[(b * 3 + k) * 32 + u] : B0[b * 32 + u];
    lWT0[b][u][k] = (_Float16)v;
  }
  for (int idx = tid; idx < 4096; idx += 256) {   // coalesced global, scattered LDS
    int b = idx >> 10, k = (idx >> 5) & 31, u = idx & 31;
    lWT1[b][u][k] = (_Float16)W1[idx];
    lWT2[b][u][k] = (_Float16)W2[idx];
  }
  for (int idx = tid; idx < 128; idx += 256) {
    int b = idx >> 5, u = idx & 31;
    lB1[b][u] = B1[idx];
    lB2[b][u] = B2[idx];
    lW3[b][u] = W3[idx];
  }
  if (tid < 4) lb3[tid] = B3[tid];
  __syncthreads();

  const int lane = tid & 63;
  const int wv = tid >> 6;
  const int g = lane >> 4;       // k-group
  const int p = lane & 15;       // point within subtile
  const bool g0 = (g == 0);
  const bool tsel = (g >= 2);    // which source tile feeds this lane's B-frag
  const int addrA = (((g & 1) << 5) | p) << 2;  // src lane 32*(g&1)+p, bytes
  const int addrB = addrA + 64;                  // src lane +16
  const int addrX16 = (lane ^ 16) << 2;
  const int addrX32 = (lane ^ 32) << 2;

  const int nblk = NPTS >> 6;    // 64 points per wave-iteration
  for (int blk = blockIdx.x * 4 + wv; blk < nblk; blk += GRID_BLOCKS * 4) {
    const int base = blk << 6;
    const float* xp = X + (size_t)(base + lane) * 3;
    float x0 = xp[0], x1 = xp[1], x2 = xp[2];

    // Branch-independent x B-fragments for the 4 subtiles (k<3: x, k==3: 1.0).
    H8 xf[4];
#pragma unroll
    for (int s = 0; s < 4; ++s) {
      int a = (16 * s + p) << 2;
      float fx0 = __int_as_float(__builtin_amdgcn_ds_bpermute(a, __float_as_int(x0)));
      float fx1 = __int_as_float(__builtin_amdgcn_ds_bpermute(a, __float_as_int(x1)));
      float fx2 = __int_as_float(__builtin_amdgcn_ds_bpermute(a, __float_as_int(x2)));
      int q0 = pkrtz(fx0, fx1);
      int q1 = pkrtz(fx2, 1.0f);
      xf[s].i[0] = g0 ? q0 : 0;
      xf[s].i[1] = g0 ? q1 : 0;
      xf[s].i[2] = 0;
      xf[s].i[3] = 0;
    }

    for (int b = 0; b < 4; ++b) {
      // Hoisted per-branch weight fragments.
      H8 w0a[2];
      h8v w1a[2], w2a[2];
      f4v bs1[2], bs2[2], w3f[2];
#pragma unroll
      for (int t = 0; t < 2; ++t) {
        const int* q = (const int*)&lWT0[b][16 * t + p][0];
        int q0 = q[0], q1 = q[1];
        w0a[t].i[0] = g0 ? q0 : 0;
        w0a[t].i[1] = g0 ? q1 : 0;
        w0a[t].i[2] = 0;
        w0a[t].i[3] = 0;
        w1a[t] = *(const h8v*)&lWT1[b][16 * t + p][8 * g];
        w2a[t] = *(const h8v*)&lWT2[b][16 * t + p][8 * g];
        bs1[t] = *(const f4v*)&lB1[b][16 * t + 4 * g];
        bs2[t] = *(const f4v*)&lB2[b][16 * t + 4 * g];
        w3f[t] = *(const f4v*)&lW3[b][16 * t + 4 * g];
      }
      float b3s = lb3[b];
      float res = 0.0f;

#pragma unroll
      for (int s = 0; s < 4; ++s) {
        f4v z = {0.f, 0.f, 0.f, 0.f};
        // L0: D = W0'^T x'^T   (bias in k==3 row)
        f4v a0 = __builtin_amdgcn_mfma_f32_16x16x32_f16(w0a[0].h, xf[s].h, z, 0, 0, 0);
        f4v a1 = __builtin_amdgcn_mfma_f32_16x16x32_f16(w0a[1].h, xf[s].h, z, 0, 0, 0);
        H8 hf = make_bfrag(a0, a1, addrA, addrB, tsel);
        // L1
        a0 = __builtin_amdgcn_mfma_f32_16x16x32_f16(w1a[0], hf.h, bs1[0], 0, 0, 0);
        a1 = __builtin_amdgcn_mfma_f32_16x16x32_f16(w1a[1], hf.h, bs1[1], 0, 0, 0);
        hf = make_bfrag(a0, a1, addrA, addrB, tsel);
        // L2
        a0 = __builtin_amdgcn_mfma_f32_16x16x32_f16(w2a[0], hf.h, bs2[0], 0, 0, 0);
        a1 = __builtin_amdgcn_mfma_f32_16x16x32_f16(w2a[1], hf.h, bs2[1], 0, 0, 0);
        // L3: tanh then dot with W3 over this lane's units, butterfly reduce.
        float t00 = ftanh(a0[0]), t01 = ftanh(a0[1]), t02 = ftanh(a0[2]), t03 = ftanh(a0[3]);
        float t10 = ftanh(a1[0]), t11 = ftanh(a1[1]), t12 = ftanh(a1[2]), t13 = ftanh(a1[3]);
        float pp = t00 * w3f[0][0];
        pp = fmaf(t01, w3f[0][1], pp);
        pp = fmaf(t02, w3f[0][2], pp);
        pp = fmaf(t03, w3f[0][3], pp);
        pp = fmaf(t10, w3f[1][0], pp);
        pp = fmaf(t11, w3f[1][1], pp);
        pp = fmaf(t12, w3f[1][2], pp);
        pp = fmaf(t13, w3f[1][3], pp);
        pp += __int_as_float(__builtin_amdgcn_ds_bpermute(addrX16, __float_as_int(pp)));
        pp += __int_as_float(__builtin_amdgcn_ds_bpermute(addrX32, __float_as_int(pp)));
        float r = pp + b3s;
        res = ((lane >> 4) == s) ? r : res;   // lane l keeps point base+l
      }
      Out[(size_t)(base + lane) * 4 + b] = res;
    }
  }
}

extern "C" void kernel_launch(void* const* d_in, const int* in_sizes, int n_in,
                              void* d_out, int out_size, void* d_ws, size_t ws_size,
                              hipStream_t stream) {
  (void)in_sizes; (void)n_in; (void)out_size; (void)d_ws; (void)ws_size;
  const float* X  = (const float*)d_in[0];
  const float* W0 = (const float*)d_in[1];
  const float* B0 = (const float*)d_in[2];
  const float* W1 = (const float*)d_in[3];
  const float* B1 = (const float*)d_in[4];
  const float* W2 = (const float*)d_in[5];
  const float* B2 = (const float*)d_in[6];
  const float* W3 = (const float*)d_in[7];
  const float* B3 = (const float*)d_in[8];
  float* Out = (float*)d_out;
  pfnn_kernel<<<dim3(GRID_BLOCKS), dim3(256), 0, stream>>>(
      X, W0, B0, W1, B1, W2, B2, W3, B3, Out);
}

// Round 2
// 173.177 us; speedup vs baseline: 1.0229x; 1.0229x over previous
//
#include <hip/hip_runtime.h>
#include <hip/hip_bf16.h>

// PFNN: out[n][b] = L3(tanh(L2(tanh(L1(tanh(L0(x)))))))  for B=4 branches,
// H=32, D_IN=3, N=1048576.  Strategy:
//  - f16 MFMA (16x16x32) computing out^T = W^T h^T per 16-point subtile.
//  - A-fragments (W^T) live in LDS (row-major [u][k], rows padded to 80B).
//  - Bias folded into MFMA C operand (layers 1,2) / into W0' row k=3 with
//    x-fragment k=3 = 1.0 (layer 0).
//  - W0..W2/b0..b2 pre-scaled by 2*log2(e) at LDS fill, so tanh needs no
//    input multiply: tanh = 1 - 2*rcp(1 + exp2(y)).
//  - Layer transition: tanh -> v_cvt_pkrtz pack -> 8x ds_bpermute
//    redistribution from D-layout (col=lane&15=point, row=4g+i=unit; m89/m91)
//    into the next B-fragment (lane holds k=8g..8g+7 for point lane&15).
//  - Layer 3 (32->1): VALU dot + butterfly reduce over lanes {p,p+16,p+32,p+48}.
//  - block=512 (8 waves), grid=1024 -> 4 blocks/CU, 32-wave/CU capacity
//    (R0 ran 256-thr blocks: occupancy capped at 50%, measured 30%).
// Regime: transcendental/VALU-bound (~403M tanh); MFMA ~9% overlapped.

#define NPTS 1048576
constexpr int GRID_BLOCKS = 1024;
constexpr int BLOCK_THREADS = 512;           // 8 waves
constexpr float TANH_SCALE = 2.885390081777927f;  // 2*log2(e)

typedef _Float16 h8v __attribute__((ext_vector_type(8)));
typedef float f4v __attribute__((ext_vector_type(4)));

union H8 { h8v h; int i[4]; };

#if __has_builtin(__builtin_amdgcn_exp2f)
#define DEV_EXP2(x) __builtin_amdgcn_exp2f(x)
#else
#define DEV_EXP2(x) __builtin_exp2f(x)
#endif
#if __has_builtin(__builtin_amdgcn_rcpf)
#define DEV_RCP(x) __builtin_amdgcn_rcpf(x)
#else
#define DEV_RCP(x) (1.0f / (x))
#endif

__device__ __forceinline__ int pkrtz(float a, float b) {
  return __builtin_bit_cast(int, __builtin_amdgcn_cvt_pkrtz(a, b));
}

// Input y is ALREADY 2*log2(e)*x (weights pre-scaled).
__device__ __forceinline__ float ftanh_s(float y) {
  float e = DEV_EXP2(y);
  float r = DEV_RCP(e + 1.0f);
  return fmaf(-2.0f, r, 1.0f);   // y->+inf: e=inf -> r=0 -> 1; y->-inf: e=0 -> -1
}

// tanh both accumulator tiles, pack to f16 pairs, redistribute into B-fragment.
__device__ __forceinline__ H8 make_bfrag(f4v a0, f4v a1, int addrA, int addrB,
                                         bool tsel) {
  float t00 = ftanh_s(a0[0]), t01 = ftanh_s(a0[1]), t02 = ftanh_s(a0[2]), t03 = ftanh_s(a0[3]);
  float t10 = ftanh_s(a1[0]), t11 = ftanh_s(a1[1]), t12 = ftanh_s(a1[2]), t13 = ftanh_s(a1[3]);
  int pk00 = pkrtz(t00, t01), pk01 = pkrtz(t02, t03);   // tile0 units (4g,4g+1),(4g+2,4g+3)
  int pk10 = pkrtz(t10, t11), pk11 = pkrtz(t12, t13);   // tile1 units 16+...
  int r0a = __builtin_amdgcn_ds_bpermute(addrA, pk00);
  int r0b = __builtin_amdgcn_ds_bpermute(addrA, pk10);
  int r1a = __builtin_amdgcn_ds_bpermute(addrA, pk01);
  int r1b = __builtin_amdgcn_ds_bpermute(addrA, pk11);
  int r2a = __builtin_amdgcn_ds_bpermute(addrB, pk00);
  int r2b = __builtin_amdgcn_ds_bpermute(addrB, pk10);
  int r3a = __builtin_amdgcn_ds_bpermute(addrB, pk01);
  int r3b = __builtin_amdgcn_ds_bpermute(addrB, pk11);
  H8 hf;
  hf.i[0] = tsel ? r0b : r0a;
  hf.i[1] = tsel ? r1b : r1a;
  hf.i[2] = tsel ? r2b : r2a;
  hf.i[3] = tsel ? r3b : r3a;
  return hf;
}

extern "C" __global__ void __launch_bounds__(BLOCK_THREADS, 8) pfnn_kernel(
    const float* __restrict__ X,
    const float* __restrict__ W0, const float* __restrict__ B0,
    const float* __restrict__ W1, const float* __restrict__ B1,
    const float* __restrict__ W2, const float* __restrict__ B2,
    const float* __restrict__ W3, const float* __restrict__ B3,
    float* __restrict__ Out) {
  // LDS: W^T tables (A-fragment source), f32 biases / last-layer weights.
  __shared__ alignas(16) _Float16 lWT0[4][32][4];    // [b][u][k] k<3: s*W0, k==3: s*b0
  __shared__ alignas(16) _Float16 lWT1[4][32][40];   // [b][u][k], rows padded to 80B
  __shared__ alignas(16) _Float16 lWT2[4][32][40];
  __shared__ alignas(16) float lB1[4][32];
  __shared__ alignas(16) float lB2[4][32];
  __shared__ alignas(16) float lW3[4][32];
  __shared__ float lb3[4];

  const int tid = threadIdx.x;
  for (int idx = tid; idx < 512; idx += BLOCK_THREADS) {
    int b = idx >> 7, u = (idx >> 2) & 31, k = idx & 3;
    float v = (k < 3) ? W0[(b * 3 + k) * 32 + u] : B0[b * 32 + u];
    lWT0[b][u][k] = (_Float16)(v * TANH_SCALE);
  }
  for (int idx = tid; idx < 4096; idx += BLOCK_THREADS) {  // coalesced global, scattered LDS
    int b = idx >> 10, k = (idx >> 5) & 31, u = idx & 31;
    lWT1[b][u][k] = (_Float16)(W1[idx] * TANH_SCALE);
    lWT2[b][u][k] = (_Float16)(W2[idx] * TANH_SCALE);
  }
  for (int idx = tid; idx < 128; idx += BLOCK_THREADS) {
    int b = idx >> 5, u = idx & 31;
    lB1[b][u] = B1[idx] * TANH_SCALE;
    lB2[b][u] = B2[idx] * TANH_SCALE;
    lW3[b][u] = W3[idx];
  }
  if (tid < 4) lb3[tid] = B3[tid];
  __syncthreads();

  const int lane = tid & 63;
  const int wv = tid >> 6;       // 0..7
  const int g = lane >> 4;       // k-group
  const int p = lane & 15;       // point within subtile
  const bool g0 = (g == 0);
  const bool tsel = (g >= 2);    // which source tile feeds this lane's B-frag
  const int addrA = (((g & 1) << 5) | p) << 2;  // src lane 32*(g&1)+p, bytes
  const int addrB = addrA + 64;                  // src lane +16
  const int addrX16 = (lane ^ 16) << 2;
  const int addrX32 = (lane ^ 32) << 2;

  const int nblk = NPTS >> 6;    // 64 points per wave-iteration
  for (int blk = blockIdx.x * 8 + wv; blk < nblk; blk += GRID_BLOCKS * 8) {
    const int base = blk << 6;
    const float* xp = X + (size_t)(base + lane) * 3;
    float x0 = xp[0], x1 = xp[1], x2 = xp[2];

    // Branch-independent x B-fragments for the 4 subtiles (k<3: x, k==3: 1.0).
    H8 xf[4];
#pragma unroll
    for (int s = 0; s < 4; ++s) {
      int a = (16 * s + p) << 2;
      float fx0 = __int_as_float(__builtin_amdgcn_ds_bpermute(a, __float_as_int(x0)));
      float fx1 = __int_as_float(__builtin_amdgcn_ds_bpermute(a, __float_as_int(x1)));
      float fx2 = __int_as_float(__builtin_amdgcn_ds_bpermute(a, __float_as_int(x2)));
      int q0 = pkrtz(fx0, fx1);
      int q1 = pkrtz(fx2, 1.0f);
      xf[s].i[0] = g0 ? q0 : 0;
      xf[s].i[1] = g0 ? q1 : 0;
      xf[s].i[2] = 0;
      xf[s].i[3] = 0;
    }

    for (int b = 0; b < 4; ++b) {
      // Hoisted per-branch weight fragments.
      H8 w0a[2];
      h8v w1a[2], w2a[2];
      f4v bs1[2], bs2[2], w3f[2];
#pragma unroll
      for (int t = 0; t < 2; ++t) {
        const int* q = (const int*)&lWT0[b][16 * t + p][0];
        int q0 = q[0], q1 = q[1];
        w0a[t].i[0] = g0 ? q0 : 0;
        w0a[t].i[1] = g0 ? q1 : 0;
        w0a[t].i[2] = 0;
        w0a[t].i[3] = 0;
        w1a[t] = *(const h8v*)&lWT1[b][16 * t + p][8 * g];
        w2a[t] = *(const h8v*)&lWT2[b][16 * t + p][8 * g];
        bs1[t] = *(const f4v*)&lB1[b][16 * t + 4 * g];
        bs2[t] = *(const f4v*)&lB2[b][16 * t + 4 * g];
        w3f[t] = *(const f4v*)&lW3[b][16 * t + 4 * g];
      }
      float b3s = lb3[b];
      float res = 0.0f;

#pragma unroll
      for (int s = 0; s < 4; ++s) {
        f4v z = {0.f, 0.f, 0.f, 0.f};
        // L0: D = W0'^T x'^T   (bias in k==3 row)
        f4v a0 = __builtin_amdgcn_mfma_f32_16x16x32_f16(w0a[0].h, xf[s].h, z, 0, 0, 0);
        f4v a1 = __builtin_amdgcn_mfma_f32_16x16x32_f16(w0a[1].h, xf[s].h, z, 0, 0, 0);
        H8 hf = make_bfrag(a0, a1, addrA, addrB, tsel);
        // L1
        a0 = __builtin_amdgcn_mfma_f32_16x16x32_f16(w1a[0], hf.h, bs1[0], 0, 0, 0);
        a1 = __builtin_amdgcn_mfma_f32_16x16x32_f16(w1a[1], hf.h, bs1[1], 0, 0, 0);
        hf = make_bfrag(a0, a1, addrA, addrB, tsel);
        // L2
        a0 = __builtin_amdgcn_mfma_f32_16x16x32_f16(w2a[0], hf.h, bs2[0], 0, 0, 0);
        a1 = __builtin_amdgcn_mfma_f32_16x16x32_f16(w2a[1], hf.h, bs2[1], 0, 0, 0);
        // L3: tanh then dot with W3 over this lane's units, butterfly reduce.
        float t00 = ftanh_s(a0[0]), t01 = ftanh_s(a0[1]), t02 = ftanh_s(a0[2]), t03 = ftanh_s(a0[3]);
        float t10 = ftanh_s(a1[0]), t11 = ftanh_s(a1[1]), t12 = ftanh_s(a1[2]), t13 = ftanh_s(a1[3]);
        float pp = t00 * w3f[0][0];
        pp = fmaf(t01, w3f[0][1], pp);
        pp = fmaf(t02, w3f[0][2], pp);
        pp = fmaf(t03, w3f[0][3], pp);
        pp = fmaf(t10, w3f[1][0], pp);
        pp = fmaf(t11, w3f[1][1], pp);
        pp = fmaf(t12, w3f[1][2], pp);
        pp = fmaf(t13, w3f[1][3], pp);
        pp += __int_as_float(__builtin_amdgcn_ds_bpermute(addrX16, __float_as_int(pp)));
        pp += __int_as_float(__builtin_amdgcn_ds_bpermute(addrX32, __float_as_int(pp)));
        float r = pp + b3s;
        res = ((lane >> 4) == s) ? r : res;   // lane l keeps point base+l
      }
      Out[(size_t)(base + lane) * 4 + b] = res;
    }
  }
}

extern "C" void kernel_launch(void* const* d_in, const int* in_sizes, int n_in,
                              void* d_out, int out_size, void* d_ws, size_t ws_size,
                              hipStream_t stream) {
  (void)in_sizes; (void)n_in; (void)out_size; (void)d_ws; (void)ws_size;
  const float* X  = (const float*)d_in[0];
  const float* W0 = (const float*)d_in[1];
  const float* B0 = (const float*)d_in[2];
  const float* W1 = (const float*)d_in[3];
  const float* B1 = (const float*)d_in[4];
  const float* W2 = (const float*)d_in[5];
  const float* B2 = (const float*)d_in[6];
  const float* W3 = (const float*)d_in[7];
  const float* B3 = (const float*)d_in[8];
  float* Out = (float*)d_out;
  pfnn_kernel<<<dim3(GRID_BLOCKS), dim3(BLOCK_THREADS), 0, stream>>>(
      X, W0, B0, W1, B1, W2, B2, W3, B3, Out);
}